// Round 6
// baseline (161.089 us; speedup 1.0000x reference)
//
#include <hip/hip_runtime.h>
#include <stdint.h>

#define NN   20000
#define HID  128
#define NE   320000
#define GEPS 1e-10f

// ======================= zero masks (replaces 93us rocclr fillBuffer!) =======================
__global__ __launch_bounds__(256) void zero_k(ulonglong2* __restrict__ p, int n16)
{
    const int t = blockIdx.x * 256 + threadIdx.x;
    if (t < n16) p[t] = make_ulonglong2(0ull, 0ull);
}

// ======================= prep: fold weights =======================
// Bbig [384][256]: rows 0..127 = W_enc; rows 128..383 (o=row-128): [W_ih[o][0:128] | W_hh[o][0:128]]
// W_comb [384][128] = W_ih[:,128:256] @ W_dec
// bias_big[384]: 0..127 = b_enc; 128..383 (o): b_ih[o]+b_hh[o]+sum_j W_ih[o][128+j]*(b_dec[j]+rowsum W_dec[j])
// bias_inn[128]: b_ih[256+o] + sum_j W_ih[256+o][128+j]*(b_dec[j]+rowsum W_dec[j])
__global__ __launch_bounds__(256) void prep_k(
    const float* __restrict__ W_enc, const float* __restrict__ b_enc,
    const float* __restrict__ W_dec, const float* __restrict__ b_dec,
    const float* __restrict__ W_ih,  const float* __restrict__ W_hh,
    const float* __restrict__ b_ih,  const float* __restrict__ b_hh,
    float* __restrict__ Bbig, float* __restrict__ bias_big,
    float* __restrict__ W_comb, float* __restrict__ bias_inn)
{
    const int b = blockIdx.x, t = threadIdx.x;
    if (b < 384) {                 // Bbig fill
        const int idx = b * 256 + t;
        const int row = idx >> 8, k = idx & 255;
        float v;
        if (row < 128) v = W_enc[row * 256 + k];
        else {
            const int o = row - 128;
            v = (k < 128) ? W_ih[o * 256 + k] : W_hh[o * 128 + (k - 128)];
        }
        Bbig[idx] = v;
    } else if (b < 576) {          // W_comb
        const int idx = (b - 384) * 256 + t;
        const int o = idx >> 7, k = idx & 127;
        float s = 0.f;
        for (int j = 0; j < 128; ++j)
            s += W_ih[o * 256 + 128 + j] * W_dec[j * 128 + k];
        W_comb[idx] = s;
    } else {                       // biases (2 blocks)
        __shared__ float bd[128];
        if (t < 128) {
            float s = b_dec[t];
            for (int k = 0; k < 128; ++k) s += W_dec[t * 128 + k];
            bd[t] = s;
        }
        __syncthreads();
        const int g = (b - 576) * 256 + t;   // 0..511
        if (g < 384) {
            float v;
            if (g < 128) v = b_enc[g];
            else {
                const int o = g - 128;
                float s = b_ih[o] + b_hh[o];
                for (int j = 0; j < 128; ++j) s += W_ih[o * 256 + 128 + j] * bd[j];
                v = s;
            }
            bias_big[g] = v;
        } else {
            const int o = g - 384;
            float s = b_ih[256 + o];
            for (int j = 0; j < 128; ++j) s += W_ih[(256 + o) * 256 + 128 + j] * bd[j];
            bias_inn[o] = s;
        }
    }
}

// ======================= big GEMM =======================
// C[M=20000, N=384] = [feat|h] @ Bbig^T + bias_big, K=256.
// n-block 0 -> epilogue writes rtab[n][j] = exp(l[2j+1]-l[2j]) (no logits stored)
// n-blocks 1,2 -> rz_sum [20000][256]
__global__ __launch_bounds__(256) void gemm_big(
    const float* __restrict__ feat, const float* __restrict__ h,
    const float* __restrict__ Bbig, const float* __restrict__ bias,
    float* __restrict__ rtab, float* __restrict__ rz)
{
    __shared__ float As[16][132];
    __shared__ float Bs[16][132];
    const int t  = threadIdx.x;
    const int n0 = blockIdx.x * 128;
    const int m0 = blockIdx.y * 128;
    const int row = t >> 2, kc = (t & 3) * 4;
    const int ty = t >> 4, tx = t & 15;

    float acc[8][8];
#pragma unroll
    for (int i = 0; i < 8; ++i)
#pragma unroll
        for (int j = 0; j < 8; ++j) acc[i][j] = 0.f;

    for (int k0 = 0; k0 < 256; k0 += 16) {
        const float* Ab = (k0 < 128) ? feat : h;
        const int ko = k0 & 127;
#pragma unroll
        for (int c = 0; c < 2; ++c) {
            const int r = row + c * 64;
            float4 v = make_float4(0.f, 0.f, 0.f, 0.f);
            if (m0 + r < NN) v = *(const float4*)(Ab + (size_t)(m0 + r) * 128 + ko + kc);
            As[kc + 0][r] = v.x; As[kc + 1][r] = v.y; As[kc + 2][r] = v.z; As[kc + 3][r] = v.w;
        }
#pragma unroll
        for (int c = 0; c < 2; ++c) {
            const int r = row + c * 64;
            const float4 v = *(const float4*)(Bbig + (size_t)(n0 + r) * 256 + k0 + kc);
            Bs[kc + 0][r] = v.x; Bs[kc + 1][r] = v.y; Bs[kc + 2][r] = v.z; Bs[kc + 3][r] = v.w;
        }
        __syncthreads();
#pragma unroll
        for (int kk = 0; kk < 16; ++kk) {
            const float4 a0 = *(const float4*)&As[kk][ty * 4];
            const float4 a1 = *(const float4*)&As[kk][64 + ty * 4];
            const float4 b0 = *(const float4*)&Bs[kk][tx * 4];
            const float4 b1 = *(const float4*)&Bs[kk][64 + tx * 4];
            const float av[8] = {a0.x, a0.y, a0.z, a0.w, a1.x, a1.y, a1.z, a1.w};
            const float bv[8] = {b0.x, b0.y, b0.z, b0.w, b1.x, b1.y, b1.z, b1.w};
#pragma unroll
            for (int i = 0; i < 8; ++i)
#pragma unroll
                for (int j = 0; j < 8; ++j) acc[i][j] = fmaf(av[i], bv[j], acc[i][j]);
        }
        __syncthreads();
    }

    float bv0[4], bv1[4];
#pragma unroll
    for (int j = 0; j < 4; ++j) { bv0[j] = bias[n0 + tx * 4 + j]; bv1[j] = bias[n0 + 64 + tx * 4 + j]; }
#pragma unroll
    for (int i = 0; i < 8; ++i) {
        const int rm = (i < 4) ? (ty * 4 + i) : (64 + ty * 4 + i - 4);
        const int gm = m0 + rm;
        if (gm >= NN) continue;
        float c0[4], c1[4];
#pragma unroll
        for (int j = 0; j < 4; ++j) { c0[j] = acc[i][j] + bv0[j]; c1[j] = acc[i][j + 4] + bv1[j]; }
        if (n0 == 0) {
            float2 r0 = make_float2(expf(c0[1] - c0[0]), expf(c0[3] - c0[2]));
            float2 r1 = make_float2(expf(c1[1] - c1[0]), expf(c1[3] - c1[2]));
            *(float2*)(rtab + (size_t)gm * 64 + tx * 2) = r0;
            *(float2*)(rtab + (size_t)gm * 64 + 32 + tx * 2) = r1;
        } else {
            *(float4*)(rz + (size_t)gm * 256 + (n0 - 128) + tx * 4) = *(const float4*)c0;
            *(float4*)(rz + (size_t)gm * 256 + (n0 - 128) + 64 + tx * 4) = *(const float4*)c1;
        }
    }
}

// ======================= inn / hn GEMM =======================
__global__ __launch_bounds__(256) void gemm_innhn(
    const float* __restrict__ feat, const float* __restrict__ h,
    const float* __restrict__ W_ih, const float* __restrict__ W_hh,
    const float* __restrict__ bias_inn, const float* __restrict__ b_hh,
    float* __restrict__ inn, float* __restrict__ hn)
{
    __shared__ float As[16][132];
    __shared__ float Bs[16][132];
    const int t = threadIdx.x;
    const int z = blockIdx.z;
    const int m0 = blockIdx.y * 128;
    const float* A   = z ? h : feat;
    const float* B   = z ? (W_hh + 256 * 128) : (W_ih + 256 * 256);
    const int    ldb = z ? 128 : 256;
    const float* bia = z ? (b_hh + 256) : bias_inn;
    float*       C   = z ? hn : inn;

    const int row = t >> 2, kc = (t & 3) * 4;
    const int ty = t >> 4, tx = t & 15;

    float acc[8][8];
#pragma unroll
    for (int i = 0; i < 8; ++i)
#pragma unroll
        for (int j = 0; j < 8; ++j) acc[i][j] = 0.f;

    for (int k0 = 0; k0 < 128; k0 += 16) {
#pragma unroll
        for (int c = 0; c < 2; ++c) {
            const int r = row + c * 64;
            float4 v = make_float4(0.f, 0.f, 0.f, 0.f);
            if (m0 + r < NN) v = *(const float4*)(A + (size_t)(m0 + r) * 128 + k0 + kc);
            As[kc + 0][r] = v.x; As[kc + 1][r] = v.y; As[kc + 2][r] = v.z; As[kc + 3][r] = v.w;
        }
#pragma unroll
        for (int c = 0; c < 2; ++c) {
            const int r = row + c * 64;
            const float4 v = *(const float4*)(B + (size_t)r * ldb + k0 + kc);
            Bs[kc + 0][r] = v.x; Bs[kc + 1][r] = v.y; Bs[kc + 2][r] = v.z; Bs[kc + 3][r] = v.w;
        }
        __syncthreads();
#pragma unroll
        for (int kk = 0; kk < 16; ++kk) {
            const float4 a0 = *(const float4*)&As[kk][ty * 4];
            const float4 a1 = *(const float4*)&As[kk][64 + ty * 4];
            const float4 b0 = *(const float4*)&Bs[kk][tx * 4];
            const float4 b1 = *(const float4*)&Bs[kk][64 + tx * 4];
            const float av[8] = {a0.x, a0.y, a0.z, a0.w, a1.x, a1.y, a1.z, a1.w};
            const float bv[8] = {b0.x, b0.y, b0.z, b0.w, b1.x, b1.y, b1.z, b1.w};
#pragma unroll
            for (int i = 0; i < 8; ++i)
#pragma unroll
                for (int j = 0; j < 8; ++j) acc[i][j] = fmaf(av[i], bv[j], acc[i][j]);
        }
        __syncthreads();
    }

    float bv0[4], bv1[4];
#pragma unroll
    for (int j = 0; j < 4; ++j) { bv0[j] = bia[tx * 4 + j]; bv1[j] = bia[64 + tx * 4 + j]; }
#pragma unroll
    for (int i = 0; i < 8; ++i) {
        const int rm = (i < 4) ? (ty * 4 + i) : (64 + ty * 4 + i - 4);
        const int gm = m0 + rm;
        if (gm >= NN) continue;
        float c0[4], c1[4];
#pragma unroll
        for (int j = 0; j < 4; ++j) { c0[j] = acc[i][j] + bv0[j]; c1[j] = acc[i][j + 4] + bv1[j]; }
        *(float4*)(C + (size_t)gm * 128 + tx * 4) = *(const float4*)c0;
        *(float4*)(C + (size_t)gm * 128 + 64 + tx * 4) = *(const float4*)c1;
    }
}

// ======================= edge kernel: 16 edges per wave =======================
// bit j: (l1+g1)>(l0+g0)  <=>  r*a0 > a1, a = eps - log(u+eps), r = exp(l1-l0)
// All 32 vector loads issued before any compute -> deep memory pipeline.
#define EPW 16
__global__ __launch_bounds__(256) void edge_k(
    const float* __restrict__ u, const int* __restrict__ src,
    const int* __restrict__ dst, const float* __restrict__ rtab,
    unsigned long long* __restrict__ masks)
{
    const int wv = __builtin_amdgcn_readfirstlane(blockIdx.x * 4 + (threadIdx.x >> 6));
    const int lane = threadIdx.x & 63;
    const int e0 = wv * EPW;

    float2 uu[EPW];
    float  rr[EPW];
    int    dd[EPW];
#pragma unroll
    for (int i = 0; i < EPW; ++i) {
        const int e = e0 + i;
        uu[i] = *(const float2*)(u + (size_t)e * 128 + lane * 2);
        rr[i] = rtab[(size_t)src[e] * 64 + lane];
        dd[i] = dst[e];
    }
#pragma unroll
    for (int i = 0; i < EPW; ++i) {
        const float a0 = GEPS - logf(uu[i].x + GEPS);
        const float a1 = GEPS - logf(uu[i].y + GEPS);
        const unsigned long long mone = __ballot(rr[i] * a0 > a1);
        if (lane == 0) {
            atomicOr(&masks[(size_t)dd[i] * 2 + 1], mone);
            atomicOr(&masks[(size_t)dd[i] * 2 + 0], ~mone);
        }
    }
}

// ======================= gates (with fused sparse correction) =======================
// rz/inn were computed with c == all-ones folded into bias; subtract W_comb columns
// for every ZERO bit of c (rare: ~e^-deg per slot; deg==0 nodes handled automatically).
__global__ __launch_bounds__(256) void gates_k(
    const float* __restrict__ rz, const float* __restrict__ inn,
    const float* __restrict__ hn, const float* __restrict__ h,
    const unsigned long long* __restrict__ masks, const float* __restrict__ W_comb,
    float* __restrict__ out)
{
    const int t = blockIdx.x * 256 + threadIdx.x;   // one float4 per thread
    const int n = t >> 5;
    const int j0 = (t & 31) * 4;
    if (n >= NN) return;

    float cr[4] = {0.f, 0.f, 0.f, 0.f};
    float cz[4] = {0.f, 0.f, 0.f, 0.f};
    float ci[4] = {0.f, 0.f, 0.f, 0.f};
    {
        unsigned long long ze = ~masks[(size_t)n * 2 + 0];
        unsigned long long zo = ~masks[(size_t)n * 2 + 1];
        if (ze | zo) {
#pragma unroll 1
            while (ze) {
                const int k = __builtin_ctzll(ze); ze &= ze - 1;
                const int bit = 2 * k;
#pragma unroll
                for (int q = 0; q < 4; ++q) {
                    cr[q] += W_comb[(j0 + q) * 128 + bit];
                    cz[q] += W_comb[(128 + j0 + q) * 128 + bit];
                    ci[q] += W_comb[(256 + j0 + q) * 128 + bit];
                }
            }
#pragma unroll 1
            while (zo) {
                const int k = __builtin_ctzll(zo); zo &= zo - 1;
                const int bit = 2 * k + 1;
#pragma unroll
                for (int q = 0; q < 4; ++q) {
                    cr[q] += W_comb[(j0 + q) * 128 + bit];
                    cz[q] += W_comb[(128 + j0 + q) * 128 + bit];
                    ci[q] += W_comb[(256 + j0 + q) * 128 + bit];
                }
            }
        }
    }

    const float4 vr = *(const float4*)(rz  + (size_t)n * 256 + j0);
    const float4 vz = *(const float4*)(rz  + (size_t)n * 256 + 128 + j0);
    const float4 vi = *(const float4*)(inn + (size_t)n * 128 + j0);
    const float4 vh = *(const float4*)(hn  + (size_t)n * 128 + j0);
    const float4 hv = *(const float4*)(h   + (size_t)n * 128 + j0);
    const float rr[4] = {vr.x, vr.y, vr.z, vr.w};
    const float zz[4] = {vz.x, vz.y, vz.z, vz.w};
    const float ii[4] = {vi.x, vi.y, vi.z, vi.w};
    const float hh[4] = {vh.x, vh.y, vh.z, vh.w};
    const float ho[4] = {hv.x, hv.y, hv.z, hv.w};
    float o[4];
#pragma unroll
    for (int q = 0; q < 4; ++q) {
        const float r = 1.f / (1.f + expf(-(rr[q] - cr[q])));
        const float z = 1.f / (1.f + expf(-(zz[q] - cz[q])));
        const float nval = tanhf((ii[q] - ci[q]) + r * hh[q]);
        o[q] = (1.f - z) * nval + z * ho[q];
    }
    float4* o4 = (float4*)o;
    *(float4*)(out + (size_t)n * 128 + j0) = *o4;
    *(float4*)(out + (size_t)(NN + n) * 128 + j0) = *o4;
}

extern "C" void kernel_launch(void* const* d_in, const int* in_sizes, int n_in,
                              void* d_out, int out_size, void* d_ws, size_t ws_size,
                              hipStream_t stream) {
    const float* feat  = (const float*)d_in[0];
    const float* h     = (const float*)d_in[1];
    const int*   src   = (const int*)d_in[2];
    const int*   dst   = (const int*)d_in[3];
    const float* u     = (const float*)d_in[4];
    const float* W_enc = (const float*)d_in[5];
    const float* b_enc = (const float*)d_in[6];
    const float* W_dec = (const float*)d_in[7];
    const float* b_dec = (const float*)d_in[8];
    const float* W_ih  = (const float*)d_in[9];
    const float* W_hh  = (const float*)d_in[10];
    const float* b_ih  = (const float*)d_in[11];
    const float* b_hh  = (const float*)d_in[12];
    float* out = (float*)d_out;
    (void)in_sizes; (void)n_in; (void)out_size; (void)ws_size;

    char* ws = (char*)d_ws;
    float*              rtab     = (float*)(ws + 0);                   //  5,120,000 B
    unsigned long long* masks    = (unsigned long long*)(ws + 5120000);//    320,000 B
    float*              Bbig     = (float*)(ws + 5440000);             //    393,216 B
    float*              bias_big = (float*)(ws + 5833216);             //      2,048 B
    float*              W_comb   = (float*)(ws + 5835264);             //    196,608 B
    float*              bias_inn = (float*)(ws + 6031872);             //      1,024 B
    float*              rz       = (float*)(ws + 6032896);             // 20,480,000 B
    float*              inn      = (float*)(ws + 26512896);            // 10,240,000 B
    float*              hn       = (float*)(ws + 36752896);            // 10,240,000 B

    // zero the OR-aggregation masks with our own kernel (rocclr fillBuffer was 93us!)
    zero_k<<<(NN * 2 * 8 / 16 + 255) / 256, 256, 0, stream>>>((ulonglong2*)masks, NN * 2 * 8 / 16);

    prep_k<<<578, 256, 0, stream>>>(W_enc, b_enc, W_dec, b_dec, W_ih, W_hh, b_ih, b_hh,
                                    Bbig, bias_big, W_comb, bias_inn);

    {   // [feat|h] @ Bbig^T : N=384 (rtab + rz), K=256
        dim3 grid(3, (NN + 127) / 128);
        gemm_big<<<grid, 256, 0, stream>>>(feat, h, Bbig, bias_big, rtab, rz);
    }

    edge_k<<<NE / (4 * EPW), 256, 0, stream>>>(u, src, dst, rtab, masks);

    {   // inn & hn, K=128
        dim3 grid(1, (NN + 127) / 128, 2);
        gemm_innhn<<<grid, 256, 0, stream>>>(feat, h, W_ih, W_hh, bias_inn, b_hh, inn, hn);
    }

    gates_k<<<(NN * 32 + 255) / 256, 256, 0, stream>>>(rz, inn, hn, h, masks, W_comb, out);
}

// Round 7
// 131.151 us; speedup vs baseline: 1.2283x; 1.2283x over previous
//
#include <hip/hip_runtime.h>
#include <stdint.h>

#define NN   20000
#define NCOL 640
#define NE   320000
#define GEPS 1e-10f

typedef __attribute__((ext_vector_type(8))) __bf16 bf16x8;
typedef __attribute__((ext_vector_type(4))) __bf16 bf16x4;
typedef __attribute__((ext_vector_type(4))) float f32x4;

// ======================= zero masks =======================
__global__ __launch_bounds__(256) void zero_k(ulonglong2* __restrict__ p, int n16)
{
    const int t = blockIdx.x * 256 + threadIdx.x;
    if (t < n16) p[t] = make_ulonglong2(0ull, 0ull);
}

// ======================= prep: pack weights to bf16 hi/lo + fold =======================
// Bpack [640][256]: rows 0-127 W_enc; 128-255 r:[W_ih|W_hh]; 256-383 z:[W_ih|W_hh];
//                   384-511 inn:[W_ih|0]; 512-639 hn:[0|W_hh]
// bias_all[640]: b_enc | r,z: b_ih+b_hh+fold | inn: b_ih+fold | hn: b_hh
// W_comb [384][128] = W_ih[:,128:256] @ W_dec  (for sparse c-correction in gates)
__global__ __launch_bounds__(256) void prep_k(
    const float* __restrict__ W_enc, const float* __restrict__ b_enc,
    const float* __restrict__ W_dec, const float* __restrict__ b_dec,
    const float* __restrict__ W_ih,  const float* __restrict__ W_hh,
    const float* __restrict__ b_ih,  const float* __restrict__ b_hh,
    __bf16* __restrict__ Bph, __bf16* __restrict__ Bpl,
    float* __restrict__ bias_all, float* __restrict__ W_comb)
{
    const int b = blockIdx.x, t = threadIdx.x;
    if (b < 640) {                       // Bpack row b
        const int n = b, k = t;
        float v;
        if (n < 128)      v = W_enc[n * 256 + k];
        else if (n < 384) { const int o = n - 128;        v = (k < 128) ? W_ih[o * 256 + k] : W_hh[o * 128 + (k - 128)]; }
        else if (n < 512) { const int o = 256 + (n - 384); v = (k < 128) ? W_ih[o * 256 + k] : 0.f; }
        else              { const int o = 256 + (n - 512); v = (k < 128) ? 0.f : W_hh[o * 128 + (k - 128)]; }
        const __bf16 hi = (__bf16)v;
        const __bf16 lo = (__bf16)(v - (float)hi);
        Bph[n * 256 + k] = hi;
        Bpl[n * 256 + k] = lo;
    } else if (b < 832) {                // W_comb
        const int idx = (b - 640) * 256 + t;
        const int o = idx >> 7, k = idx & 127;
        float s = 0.f;
        for (int j = 0; j < 128; ++j)
            s += W_ih[o * 256 + 128 + j] * W_dec[j * 128 + k];
        W_comb[idx] = s;
    } else {                             // biases (3 blocks)
        __shared__ float bd[128];
        if (t < 128) {
            float s = b_dec[t];
            for (int k = 0; k < 128; ++k) s += W_dec[t * 128 + k];
            bd[t] = s;
        }
        __syncthreads();
        const int g = (b - 832) * 256 + t;
        if (g >= 640) return;
        float v;
        if (g < 128) v = b_enc[g];
        else if (g < 384) {
            const int o = g - 128;
            float s = b_ih[o] + b_hh[o];
            for (int j = 0; j < 128; ++j) s += W_ih[o * 256 + 128 + j] * bd[j];
            v = s;
        } else if (g < 512) {
            const int o = 256 + (g - 384);
            float s = b_ih[o];
            for (int j = 0; j < 128; ++j) s += W_ih[o * 256 + 128 + j] * bd[j];
            v = s;
        } else v = b_hh[256 + (g - 512)];
        bias_all[g] = v;
    }
}

// ======================= split-bf16 MFMA GEMM =======================
// C[20000][640] = [feat|h](fp32->hi/lo bf16) @ Bpack^T + bias, K=256
// x = hi + lo; A*B ~= Ah*Bh + Al*Bh + Ah*Bl  (error ~2^-17 relative)
__device__ __forceinline__ int lds_off(int r, int k) {
    // [128][32] bf16 buffer, 16B-unit XOR swizzle to spread banks
    return r * 32 + ((((k >> 3) ^ (r >> 1)) & 3) << 3) + (k & 7);
}

__global__ __launch_bounds__(256) void gemm_mfma(
    const float* __restrict__ feat, const float* __restrict__ h,
    const __bf16* __restrict__ Bph, const __bf16* __restrict__ Bpl,
    const float* __restrict__ bias_all, float* __restrict__ C)
{
    __shared__ __bf16 sAh[4096], sAl[4096], sBh[4096], sBl[4096];
    const int t = threadIdx.x;
    const int n0 = blockIdx.x * 128, m0 = blockIdx.y * 128;
    const int lane = t & 63, wid = t >> 6;
    const int wm = (wid >> 1) * 64, wn = (wid & 1) * 64;
    const int fr = lane & 15, fk = (lane >> 4) * 8;
    const int sr = t & 127, skh = (t >> 7) * 16;

    f32x4 acc[4][4];
#pragma unroll
    for (int i = 0; i < 4; ++i)
#pragma unroll
        for (int j = 0; j < 4; ++j) acc[i][j] = (f32x4){0.f, 0.f, 0.f, 0.f};

    for (int kt = 0; kt < 8; ++kt) {
        __syncthreads();
        {   // ---- stage A: fp32 -> (hi,lo) bf16 ----
            const float* Ab = (kt < 4) ? feat : h;
            const int gk = (kt & 3) * 32 + skh;
            const int gm = m0 + sr;
            float x[16];
            if (gm < NN) {
#pragma unroll
                for (int q = 0; q < 4; ++q) {
                    const float4 v = *(const float4*)(Ab + (size_t)gm * 128 + gk + q * 4);
                    x[q * 4 + 0] = v.x; x[q * 4 + 1] = v.y; x[q * 4 + 2] = v.z; x[q * 4 + 3] = v.w;
                }
            } else {
#pragma unroll
                for (int q = 0; q < 16; ++q) x[q] = 0.f;
            }
#pragma unroll
            for (int a = 0; a < 4; ++a) {
                bf16x4 h4, l4;
#pragma unroll
                for (int i = 0; i < 4; ++i) {
                    const float xv = x[a * 4 + i];
                    const __bf16 hv = (__bf16)xv;
                    h4[i] = hv;
                    l4[i] = (__bf16)(xv - (float)hv);
                }
                *(bf16x4*)&sAh[lds_off(sr, skh + a * 4)] = h4;
                *(bf16x4*)&sAl[lds_off(sr, skh + a * 4)] = l4;
            }
        }
        {   // ---- stage B: prepacked bf16 ----
            const __bf16* gbh = Bph + (size_t)(n0 + sr) * 256 + kt * 32 + skh;
            const __bf16* gbl = Bpl + (size_t)(n0 + sr) * 256 + kt * 32 + skh;
            *(bf16x8*)&sBh[lds_off(sr, skh)]     = *(const bf16x8*)gbh;
            *(bf16x8*)&sBh[lds_off(sr, skh + 8)] = *(const bf16x8*)(gbh + 8);
            *(bf16x8*)&sBl[lds_off(sr, skh)]     = *(const bf16x8*)gbl;
            *(bf16x8*)&sBl[lds_off(sr, skh + 8)] = *(const bf16x8*)(gbl + 8);
        }
        __syncthreads();

        bf16x8 ah[4], al[4], bh[4], bl[4];
#pragma unroll
        for (int f = 0; f < 4; ++f) {
            ah[f] = *(bf16x8*)&sAh[lds_off(wm + f * 16 + fr, fk)];
            al[f] = *(bf16x8*)&sAl[lds_off(wm + f * 16 + fr, fk)];
            bh[f] = *(bf16x8*)&sBh[lds_off(wn + f * 16 + fr, fk)];
            bl[f] = *(bf16x8*)&sBl[lds_off(wn + f * 16 + fr, fk)];
        }
#pragma unroll
        for (int mf = 0; mf < 4; ++mf)
#pragma unroll
            for (int nf = 0; nf < 4; ++nf) {
                acc[mf][nf] = __builtin_amdgcn_mfma_f32_16x16x32_bf16(ah[mf], bh[nf], acc[mf][nf], 0, 0, 0);
                acc[mf][nf] = __builtin_amdgcn_mfma_f32_16x16x32_bf16(al[mf], bh[nf], acc[mf][nf], 0, 0, 0);
                acc[mf][nf] = __builtin_amdgcn_mfma_f32_16x16x32_bf16(ah[mf], bl[nf], acc[mf][nf], 0, 0, 0);
            }
    }

    // ---- epilogue: C/D layout col=lane&15, row=(lane>>4)*4+rr ----
#pragma unroll
    for (int nf = 0; nf < 4; ++nf) {
        const int gc = n0 + wn + nf * 16 + fr;
        const float bia = bias_all[gc];
#pragma unroll
        for (int mf = 0; mf < 4; ++mf) {
#pragma unroll
            for (int rr = 0; rr < 4; ++rr) {
                const int gr = m0 + wm + mf * 16 + (lane >> 4) * 4 + rr;
                if (gr < NN) C[(size_t)gr * NCOL + gc] = acc[mf][nf][rr] + bia;
            }
        }
    }
}

// ======================= rtab: exp(l[2j+1]-l[2j]) from C cols 0..127 =======================
__global__ __launch_bounds__(256) void rtab_k(const float* __restrict__ C, float* __restrict__ rtab)
{
    const int t = blockIdx.x * 256 + threadIdx.x;
    const int n = t >> 4;
    const int jj = (t & 15) * 8;
    if (n >= NN) return;
    const float4 c0 = *(const float4*)(C + (size_t)n * NCOL + jj);
    const float4 c1 = *(const float4*)(C + (size_t)n * NCOL + jj + 4);
    float4 o;
    o.x = expf(c0.y - c0.x);
    o.y = expf(c0.w - c0.z);
    o.z = expf(c1.y - c1.x);
    o.w = expf(c1.w - c1.z);
    *(float4*)(rtab + (size_t)n * 64 + jj / 2) = o;
}

// ======================= edge kernel: 16 edges per wave =======================
#define EPW 16
__global__ __launch_bounds__(256) void edge_k(
    const float* __restrict__ u, const int* __restrict__ src,
    const int* __restrict__ dst, const float* __restrict__ rtab,
    unsigned long long* __restrict__ masks)
{
    const int wv = __builtin_amdgcn_readfirstlane(blockIdx.x * 4 + (threadIdx.x >> 6));
    const int lane = threadIdx.x & 63;
    const int e0 = wv * EPW;

    float2 uu[EPW];
    float  rr[EPW];
    int    dd[EPW];
#pragma unroll
    for (int i = 0; i < EPW; ++i) {
        const int e = e0 + i;
        uu[i] = *(const float2*)(u + (size_t)e * 128 + lane * 2);
        rr[i] = rtab[(size_t)src[e] * 64 + lane];
        dd[i] = dst[e];
    }
#pragma unroll
    for (int i = 0; i < EPW; ++i) {
        const float a0 = GEPS - logf(uu[i].x + GEPS);
        const float a1 = GEPS - logf(uu[i].y + GEPS);
        const unsigned long long mone = __ballot(rr[i] * a0 > a1);
        if (lane == 0) {
            atomicOr(&masks[(size_t)dd[i] * 2 + 1], mone);
            atomicOr(&masks[(size_t)dd[i] * 2 + 0], ~mone);
        }
    }
}

// ======================= gates (fused sparse c-correction) =======================
__global__ __launch_bounds__(256) void gates_k(
    const float* __restrict__ C, const float* __restrict__ h,
    const unsigned long long* __restrict__ masks, const float* __restrict__ W_comb,
    float* __restrict__ out)
{
    const int t = blockIdx.x * 256 + threadIdx.x;
    const int n = t >> 5;
    const int j0 = (t & 31) * 4;
    if (n >= NN) return;

    float cr[4] = {0.f, 0.f, 0.f, 0.f};
    float cz[4] = {0.f, 0.f, 0.f, 0.f};
    float ci[4] = {0.f, 0.f, 0.f, 0.f};
    {
        unsigned long long ze = ~masks[(size_t)n * 2 + 0];
        unsigned long long zo = ~masks[(size_t)n * 2 + 1];
        if (ze | zo) {
#pragma unroll 1
            while (ze) {
                const int k = __builtin_ctzll(ze); ze &= ze - 1;
                const int bit = 2 * k;
#pragma unroll
                for (int q = 0; q < 4; ++q) {
                    cr[q] += W_comb[(j0 + q) * 128 + bit];
                    cz[q] += W_comb[(128 + j0 + q) * 128 + bit];
                    ci[q] += W_comb[(256 + j0 + q) * 128 + bit];
                }
            }
#pragma unroll 1
            while (zo) {
                const int k = __builtin_ctzll(zo); zo &= zo - 1;
                const int bit = 2 * k + 1;
#pragma unroll
                for (int q = 0; q < 4; ++q) {
                    cr[q] += W_comb[(j0 + q) * 128 + bit];
                    cz[q] += W_comb[(128 + j0 + q) * 128 + bit];
                    ci[q] += W_comb[(256 + j0 + q) * 128 + bit];
                }
            }
        }
    }

    const float* Cn = C + (size_t)n * NCOL;
    const float4 vr = *(const float4*)(Cn + 128 + j0);
    const float4 vz = *(const float4*)(Cn + 256 + j0);
    const float4 vi = *(const float4*)(Cn + 384 + j0);
    const float4 vh = *(const float4*)(Cn + 512 + j0);
    const float4 hv = *(const float4*)(h + (size_t)n * 128 + j0);
    const float rr[4] = {vr.x, vr.y, vr.z, vr.w};
    const float zz[4] = {vz.x, vz.y, vz.z, vz.w};
    const float ii[4] = {vi.x, vi.y, vi.z, vi.w};
    const float hh[4] = {vh.x, vh.y, vh.z, vh.w};
    const float ho[4] = {hv.x, hv.y, hv.z, hv.w};
    float o[4];
#pragma unroll
    for (int q = 0; q < 4; ++q) {
        const float r = 1.f / (1.f + expf(-(rr[q] - cr[q])));
        const float z = 1.f / (1.f + expf(-(zz[q] - cz[q])));
        const float nval = tanhf((ii[q] - ci[q]) + r * hh[q]);
        o[q] = (1.f - z) * nval + z * ho[q];
    }
    float4* o4 = (float4*)o;
    *(float4*)(out + (size_t)n * 128 + j0) = *o4;
    *(float4*)(out + (size_t)(NN + n) * 128 + j0) = *o4;
}

extern "C" void kernel_launch(void* const* d_in, const int* in_sizes, int n_in,
                              void* d_out, int out_size, void* d_ws, size_t ws_size,
                              hipStream_t stream) {
    const float* feat  = (const float*)d_in[0];
    const float* h     = (const float*)d_in[1];
    const int*   src   = (const int*)d_in[2];
    const int*   dst   = (const int*)d_in[3];
    const float* u     = (const float*)d_in[4];
    const float* W_enc = (const float*)d_in[5];
    const float* b_enc = (const float*)d_in[6];
    const float* W_dec = (const float*)d_in[7];
    const float* b_dec = (const float*)d_in[8];
    const float* W_ih  = (const float*)d_in[9];
    const float* W_hh  = (const float*)d_in[10];
    const float* b_ih  = (const float*)d_in[11];
    const float* b_hh  = (const float*)d_in[12];
    float* out = (float*)d_out;
    (void)in_sizes; (void)n_in; (void)out_size; (void)ws_size;

    char* ws = (char*)d_ws;
    float*              Cbuf     = (float*)(ws + 0);                    // 51,200,000 B
    float*              rtab     = (float*)(ws + 51200000);             //  5,120,000 B
    unsigned long long* masks    = (unsigned long long*)(ws + 56320000);//    320,000 B
    __bf16*             Bph      = (__bf16*)(ws + 56640000);            //    327,680 B
    __bf16*             Bpl      = (__bf16*)(ws + 56967680);            //    327,680 B
    float*              bias_all = (float*)(ws + 57295360);             //      2,560 B
    float*              W_comb   = (float*)(ws + 57297920);             //    196,608 B

    zero_k<<<(NN * 2 * 8 / 16 + 255) / 256, 256, 0, stream>>>((ulonglong2*)masks, NN * 2 * 8 / 16);

    prep_k<<<835, 256, 0, stream>>>(W_enc, b_enc, W_dec, b_dec, W_ih, W_hh, b_ih, b_hh,
                                    Bph, Bpl, bias_all, W_comb);

    {   // C[20000][640] = [feat|h] @ Bpack^T + bias  (split-bf16 MFMA)
        dim3 grid(NCOL / 128, (NN + 127) / 128);
        gemm_mfma<<<grid, 256, 0, stream>>>(feat, h, Bph, Bpl, bias_all, Cbuf);
    }

    rtab_k<<<(NN * 16 + 255) / 256, 256, 0, stream>>>(Cbuf, rtab);

    edge_k<<<NE / (4 * EPW), 256, 0, stream>>>(u, src, dst, rtab, masks);

    gates_k<<<(NN * 32 + 255) / 256, 256, 0, stream>>>(Cbuf, h, masks, W_comb, out);
}

// Round 8
// 124.042 us; speedup vs baseline: 1.2987x; 1.0573x over previous
//
#include <hip/hip_runtime.h>
#include <stdint.h>

#define NN   20000
#define NE   320000
#define GEPS 1e-10f

typedef __attribute__((ext_vector_type(8))) __bf16 bf16x8;
typedef __attribute__((ext_vector_type(4))) __bf16 bf16x4;
typedef __attribute__((ext_vector_type(4))) float f32x4;

// [128][32] bf16 LDS tile, 16B-unit XOR swizzle
__device__ __forceinline__ int lds_off(int r, int k) {
    return r * 32 + ((((k >> 3) ^ (r >> 1)) & 3) << 3) + (k & 7);
}

// stage 128x32 fp32 A-panel ([feat|h]) as split hi/lo bf16 into LDS
__device__ __forceinline__ void stage_A(const float* __restrict__ feat, const float* __restrict__ h,
                                        int kt, int m0, int sr, int skh,
                                        __bf16* sAh, __bf16* sAl)
{
    const float* Ab = (kt < 4) ? feat : h;
    const int gk = (kt & 3) * 32 + skh;
    const int gm = m0 + sr;
    float x[16];
    if (gm < NN) {
#pragma unroll
        for (int q = 0; q < 4; ++q) {
            const float4 v = *(const float4*)(Ab + (size_t)gm * 128 + gk + q * 4);
            x[q * 4 + 0] = v.x; x[q * 4 + 1] = v.y; x[q * 4 + 2] = v.z; x[q * 4 + 3] = v.w;
        }
    } else {
#pragma unroll
        for (int q = 0; q < 16; ++q) x[q] = 0.f;
    }
#pragma unroll
    for (int a = 0; a < 4; ++a) {
        bf16x4 h4, l4;
#pragma unroll
        for (int i = 0; i < 4; ++i) {
            const float xv = x[a * 4 + i];
            const __bf16 hv = (__bf16)xv;
            h4[i] = hv;
            l4[i] = (__bf16)(xv - (float)hv);
        }
        *(bf16x4*)&sAh[lds_off(sr, skh + a * 4)] = h4;
        *(bf16x4*)&sAl[lds_off(sr, skh + a * 4)] = l4;
    }
}

// ======================= prep: pack/permute weights, fold biases, zero masks =======================
// B1 [128][256]: permuted W_enc rows: row c -> W_enc[ (c>>6)*64 + (c&31)*2 + ((c>>5)&1) ]
//   (so a wave's even cols nf{0,1} pair with odd cols nf{2,3} in the same lane)
// B2 [512][256]: row nb*128+g*32+jj -> gate g of hidden dim j=nb*32+jj;
//   g=0 r:[W_ih_r|W_hh_r], g=1 z, g=2 inn:[W_ih|0], g=3 hn:[0|W_hh]
// bias1[128] permuted b_enc; bias2[512]: r,z: b_ih+b_hh+fold(c=1); inn: b_ih+fold; hn: b_hh
// W_comb [384][128] = W_ih[:,128:256] @ W_dec (sparse zero-bit correction)
__global__ __launch_bounds__(256) void prep_k(
    const float* __restrict__ W_enc, const float* __restrict__ b_enc,
    const float* __restrict__ W_dec, const float* __restrict__ b_dec,
    const float* __restrict__ W_ih,  const float* __restrict__ W_hh,
    const float* __restrict__ b_ih,  const float* __restrict__ b_hh,
    __bf16* __restrict__ B1h, __bf16* __restrict__ B1l,
    __bf16* __restrict__ B2h, __bf16* __restrict__ B2l,
    float* __restrict__ bias1, float* __restrict__ bias2,
    float* __restrict__ W_comb, ulonglong2* __restrict__ mask2)
{
    const int b = blockIdx.x, t = threadIdx.x;
    if (b < 128) {
        const int src = (b >> 6) * 64 + (b & 31) * 2 + ((b >> 5) & 1);
        const float v = W_enc[src * 256 + t];
        const __bf16 hi = (__bf16)v;
        B1h[b * 256 + t] = hi;
        B1l[b * 256 + t] = (__bf16)(v - (float)hi);
    } else if (b < 640) {
        const int r2 = b - 128;
        const int nb = r2 >> 7, rem = r2 & 127, g = rem >> 5, jj = rem & 31;
        const int j = nb * 32 + jj;
        const int k = t;
        float v;
        if (g == 0)      v = (k < 128) ? W_ih[j * 256 + k]         : W_hh[j * 128 + (k - 128)];
        else if (g == 1) v = (k < 128) ? W_ih[(128 + j) * 256 + k] : W_hh[(128 + j) * 128 + (k - 128)];
        else if (g == 2) v = (k < 128) ? W_ih[(256 + j) * 256 + k] : 0.f;
        else             v = (k < 128) ? 0.f                       : W_hh[(256 + j) * 128 + (k - 128)];
        const __bf16 hi = (__bf16)v;
        B2h[r2 * 256 + t] = hi;
        B2l[r2 * 256 + t] = (__bf16)(v - (float)hi);
    } else if (b < 832) {
        const int idx = (b - 640) * 256 + t;
        const int o = idx >> 7, k = idx & 127;
        float s = 0.f;
        for (int l = 0; l < 128; ++l)
            s += W_ih[o * 256 + 128 + l] * W_dec[l * 128 + k];
        W_comb[idx] = s;
    } else if (b < 835) {
        __shared__ float bd[128];
        if (t < 128) {
            float s = b_dec[t];
            for (int k = 0; k < 128; ++k) s += W_dec[t * 128 + k];
            bd[t] = s;
        }
        __syncthreads();
        const int g = (b - 832) * 256 + t;   // 0..767
        if (g < 128) {
            bias1[g] = b_enc[(g >> 6) * 64 + (g & 31) * 2 + ((g >> 5) & 1)];
        } else if (g < 640) {
            const int c2 = g - 128;
            const int nb = c2 >> 7, rem = c2 & 127, gg = rem >> 5, jj = rem & 31;
            const int j = nb * 32 + jj;
            float v;
            if (gg == 3) v = b_hh[256 + j];
            else {
                const int o = gg * 128 + j;
                float s = (gg == 2) ? b_ih[o] : (b_ih[o] + b_hh[o]);
                for (int l = 0; l < 128; ++l) s += W_ih[o * 256 + 128 + l] * bd[l];
                v = s;
            }
            bias2[c2] = v;
        }
    } else {
        const int i = (b - 835) * 256 + t;
        if (i < NN) mask2[i] = make_ulonglong2(0ull, 0ull);
    }
}

// ======================= GEMM1: logits -> rtab (fused epilogue) =======================
__global__ __launch_bounds__(256) void gemm_rtab(
    const float* __restrict__ feat, const float* __restrict__ h,
    const __bf16* __restrict__ B1h, const __bf16* __restrict__ B1l,
    const float* __restrict__ bias1, float* __restrict__ rtab)
{
    __shared__ __bf16 sAh[4096], sAl[4096], sBh[4096], sBl[4096];
    const int t = threadIdx.x, m0 = blockIdx.x * 128;
    const int lane = t & 63, wid = t >> 6;
    const int wm = (wid >> 1) * 64, wn = (wid & 1) * 64;
    const int fr = lane & 15, fk = (lane >> 4) * 8;
    const int sr = t & 127, skh = (t >> 7) * 16;

    f32x4 acc[4][4];
#pragma unroll
    for (int i = 0; i < 4; ++i)
#pragma unroll
        for (int j = 0; j < 4; ++j) acc[i][j] = (f32x4){0.f, 0.f, 0.f, 0.f};

    for (int kt = 0; kt < 8; ++kt) {
        __syncthreads();
        stage_A(feat, h, kt, m0, sr, skh, sAh, sAl);
        {
            const __bf16* gbh = B1h + (size_t)sr * 256 + kt * 32 + skh;
            const __bf16* gbl = B1l + (size_t)sr * 256 + kt * 32 + skh;
            *(bf16x8*)&sBh[lds_off(sr, skh)]     = *(const bf16x8*)gbh;
            *(bf16x8*)&sBh[lds_off(sr, skh + 8)] = *(const bf16x8*)(gbh + 8);
            *(bf16x8*)&sBl[lds_off(sr, skh)]     = *(const bf16x8*)gbl;
            *(bf16x8*)&sBl[lds_off(sr, skh + 8)] = *(const bf16x8*)(gbl + 8);
        }
        __syncthreads();

        bf16x8 ah[4], al[4], bh[4], bl[4];
#pragma unroll
        for (int f = 0; f < 4; ++f) {
            ah[f] = *(bf16x8*)&sAh[lds_off(wm + f * 16 + fr, fk)];
            al[f] = *(bf16x8*)&sAl[lds_off(wm + f * 16 + fr, fk)];
            bh[f] = *(bf16x8*)&sBh[lds_off(wn + f * 16 + fr, fk)];
            bl[f] = *(bf16x8*)&sBl[lds_off(wn + f * 16 + fr, fk)];
        }
#pragma unroll
        for (int mf = 0; mf < 4; ++mf)
#pragma unroll
            for (int nf = 0; nf < 4; ++nf) {
                acc[mf][nf] = __builtin_amdgcn_mfma_f32_16x16x32_bf16(ah[mf], bh[nf], acc[mf][nf], 0, 0, 0);
                acc[mf][nf] = __builtin_amdgcn_mfma_f32_16x16x32_bf16(al[mf], bh[nf], acc[mf][nf], 0, 0, 0);
                acc[mf][nf] = __builtin_amdgcn_mfma_f32_16x16x32_bf16(ah[mf], bl[nf], acc[mf][nf], 0, 0, 0);
            }
    }

    // epilogue: pair (even nf, odd nf+2) in same lane -> r = exp(l1-l0)
#pragma unroll
    for (int nf = 0; nf < 2; ++nf) {
        const int c0 = wn + nf * 16 + fr;
        const float b0 = bias1[c0], b1 = bias1[c0 + 32];
        const int j = (wid & 1) * 32 + nf * 16 + fr;
#pragma unroll
        for (int mf = 0; mf < 4; ++mf)
#pragma unroll
            for (int rr = 0; rr < 4; ++rr) {
                const int gr = m0 + wm + mf * 16 + (lane >> 4) * 4 + rr;
                if (gr < NN)
                    rtab[(size_t)gr * 64 + j] =
                        expf((acc[mf][nf + 2][rr] + b1) - (acc[mf][nf][rr] + b0));
            }
    }
}

// ======================= edge kernel: 16 edges per wave =======================
#define EPW 16
__global__ __launch_bounds__(256) void edge_k(
    const float* __restrict__ u, const int* __restrict__ src,
    const int* __restrict__ dst, const float* __restrict__ rtab,
    unsigned long long* __restrict__ masks)
{
    const int wv = __builtin_amdgcn_readfirstlane(blockIdx.x * 4 + (threadIdx.x >> 6));
    const int lane = threadIdx.x & 63;
    const int e0 = wv * EPW;

    float2 uu[EPW];
    float  rr[EPW];
    int    dd[EPW];
#pragma unroll
    for (int i = 0; i < EPW; ++i) {
        const int e = e0 + i;
        uu[i] = *(const float2*)(u + (size_t)e * 128 + lane * 2);
        rr[i] = rtab[(size_t)src[e] * 64 + lane];
        dd[i] = dst[e];
    }
#pragma unroll
    for (int i = 0; i < EPW; ++i) {
        const float a0 = GEPS - logf(uu[i].x + GEPS);
        const float a1 = GEPS - logf(uu[i].y + GEPS);
        const unsigned long long mone = __ballot(rr[i] * a0 > a1);
        if (lane == 0) {
            atomicOr(&masks[(size_t)dd[i] * 2 + 1], mone);
            atomicOr(&masks[(size_t)dd[i] * 2 + 0], ~mone);
        }
    }
}

// ======================= GEMM2: r/z/inn/hn + fused GRU gate epilogue =======================
// block (nb, mb): rows mb*128..+127, hidden dims j in [nb*32, nb*32+32)
// wave wid: rows wm=wid*32; acc[mf in 0..1][nf=g*2+jh] covers col nf*16+fr
__global__ __launch_bounds__(256) void gemm_gates(
    const float* __restrict__ feat, const float* __restrict__ h,
    const __bf16* __restrict__ B2h, const __bf16* __restrict__ B2l,
    const float* __restrict__ bias2, const unsigned long long* __restrict__ masks,
    const float* __restrict__ W_comb, float* __restrict__ out)
{
    __shared__ __bf16 sAh[4096], sAl[4096], sBh[4096], sBl[4096];
    const int t = threadIdx.x;
    const int nb = blockIdx.x, m0 = blockIdx.y * 128;
    const int lane = t & 63, wid = t >> 6;
    const int wm = wid * 32;
    const int fr = lane & 15, fk = (lane >> 4) * 8;
    const int sr = t & 127, skh = (t >> 7) * 16;

    f32x4 acc[2][8];
#pragma unroll
    for (int i = 0; i < 2; ++i)
#pragma unroll
        for (int j = 0; j < 8; ++j) acc[i][j] = (f32x4){0.f, 0.f, 0.f, 0.f};

    for (int kt = 0; kt < 8; ++kt) {
        __syncthreads();
        stage_A(feat, h, kt, m0, sr, skh, sAh, sAl);
        {
            const __bf16* gbh = B2h + (size_t)(nb * 128 + sr) * 256 + kt * 32 + skh;
            const __bf16* gbl = B2l + (size_t)(nb * 128 + sr) * 256 + kt * 32 + skh;
            *(bf16x8*)&sBh[lds_off(sr, skh)]     = *(const bf16x8*)gbh;
            *(bf16x8*)&sBh[lds_off(sr, skh + 8)] = *(const bf16x8*)(gbh + 8);
            *(bf16x8*)&sBl[lds_off(sr, skh)]     = *(const bf16x8*)gbl;
            *(bf16x8*)&sBl[lds_off(sr, skh + 8)] = *(const bf16x8*)(gbl + 8);
        }
        __syncthreads();

        bf16x8 ah[2], al[2], bh[8], bl[8];
#pragma unroll
        for (int f = 0; f < 2; ++f) {
            ah[f] = *(bf16x8*)&sAh[lds_off(wm + f * 16 + fr, fk)];
            al[f] = *(bf16x8*)&sAl[lds_off(wm + f * 16 + fr, fk)];
        }
#pragma unroll
        for (int f = 0; f < 8; ++f) {
            bh[f] = *(bf16x8*)&sBh[lds_off(f * 16 + fr, fk)];
            bl[f] = *(bf16x8*)&sBl[lds_off(f * 16 + fr, fk)];
        }
#pragma unroll
        for (int mf = 0; mf < 2; ++mf)
#pragma unroll
            for (int nf = 0; nf < 8; ++nf) {
                acc[mf][nf] = __builtin_amdgcn_mfma_f32_16x16x32_bf16(ah[mf], bh[nf], acc[mf][nf], 0, 0, 0);
                acc[mf][nf] = __builtin_amdgcn_mfma_f32_16x16x32_bf16(al[mf], bh[nf], acc[mf][nf], 0, 0, 0);
                acc[mf][nf] = __builtin_amdgcn_mfma_f32_16x16x32_bf16(ah[mf], bl[nf], acc[mf][nf], 0, 0, 0);
            }
    }

    // ---- fused GRU epilogue ----
    float bia[8];
#pragma unroll
    for (int nf = 0; nf < 8; ++nf) bia[nf] = bias2[nb * 128 + nf * 16 + fr];

#pragma unroll
    for (int mf = 0; mf < 2; ++mf)
#pragma unroll
        for (int rr = 0; rr < 4; ++rr) {
            const int gr = m0 + wm + mf * 16 + (lane >> 4) * 4 + rr;
            if (gr >= NN) continue;
            const unsigned long long ze = ~masks[(size_t)gr * 2 + 0];
            const unsigned long long zo = ~masks[(size_t)gr * 2 + 1];
#pragma unroll
            for (int jh = 0; jh < 2; ++jh) {
                const int j = nb * 32 + jh * 16 + fr;
                float rp = acc[mf][0 + jh][rr] + bia[0 + jh];
                float zp = acc[mf][2 + jh][rr] + bia[2 + jh];
                float ip = acc[mf][4 + jh][rr] + bia[4 + jh];
                float hp = acc[mf][6 + jh][rr] + bia[6 + jh];
                if (ze | zo) {
                    unsigned long long bz = ze;
#pragma unroll 1
                    while (bz) {
                        const int k = __builtin_ctzll(bz); bz &= bz - 1;
                        const int bit = 2 * k;
                        rp -= W_comb[(size_t)j * 128 + bit];
                        zp -= W_comb[(size_t)(128 + j) * 128 + bit];
                        ip -= W_comb[(size_t)(256 + j) * 128 + bit];
                    }
                    bz = zo;
#pragma unroll 1
                    while (bz) {
                        const int k = __builtin_ctzll(bz); bz &= bz - 1;
                        const int bit = 2 * k + 1;
                        rp -= W_comb[(size_t)j * 128 + bit];
                        zp -= W_comb[(size_t)(128 + j) * 128 + bit];
                        ip -= W_comb[(size_t)(256 + j) * 128 + bit];
                    }
                }
                const float hv = h[(size_t)gr * 128 + j];
                const float rg = 1.f / (1.f + expf(-rp));
                const float zg = 1.f / (1.f + expf(-zp));
                const float nv = tanhf(ip + rg * hp);
                const float o = (1.f - zg) * nv + zg * hv;
                out[(size_t)gr * 128 + j] = o;
                out[(size_t)(NN + gr) * 128 + j] = o;
            }
        }
}

extern "C" void kernel_launch(void* const* d_in, const int* in_sizes, int n_in,
                              void* d_out, int out_size, void* d_ws, size_t ws_size,
                              hipStream_t stream) {
    const float* feat  = (const float*)d_in[0];
    const float* h     = (const float*)d_in[1];
    const int*   src   = (const int*)d_in[2];
    const int*   dst   = (const int*)d_in[3];
    const float* u     = (const float*)d_in[4];
    const float* W_enc = (const float*)d_in[5];
    const float* b_enc = (const float*)d_in[6];
    const float* W_dec = (const float*)d_in[7];
    const float* b_dec = (const float*)d_in[8];
    const float* W_ih  = (const float*)d_in[9];
    const float* W_hh  = (const float*)d_in[10];
    const float* b_ih  = (const float*)d_in[11];
    const float* b_hh  = (const float*)d_in[12];
    float* out = (float*)d_out;
    (void)in_sizes; (void)n_in; (void)out_size; (void)ws_size;

    char* ws = (char*)d_ws;
    float*              rtab   = (float*)(ws + 0);                    // 5,120,000 B
    unsigned long long* masks  = (unsigned long long*)(ws + 5120000); //   320,000 B
    __bf16*             B1h    = (__bf16*)(ws + 5440000);             //    65,536 B
    __bf16*             B1l    = (__bf16*)(ws + 5505536);             //    65,536 B
    __bf16*             B2h    = (__bf16*)(ws + 5571072);             //   262,144 B
    __bf16*             B2l    = (__bf16*)(ws + 5833216);             //   262,144 B
    float*              bias1  = (float*)(ws + 6095360);              //       512 B
    float*              bias2  = (float*)(ws + 6095872);              //     2,048 B
    float*              W_comb = (float*)(ws + 6097920);              //   196,608 B

    // pack weights + fold biases + zero masks (one launch)
    prep_k<<<835 + (NN + 255) / 256, 256, 0, stream>>>(
        W_enc, b_enc, W_dec, b_dec, W_ih, W_hh, b_ih, b_hh,
        B1h, B1l, B2h, B2l, bias1, bias2, W_comb, (ulonglong2*)masks);

    // logits GEMM -> rtab (M=20000, N=128, K=256)
    gemm_rtab<<<(NN + 127) / 128, 256, 0, stream>>>(feat, h, B1h, B1l, bias1, rtab);

    // per-edge gumbel argmax -> OR masks
    edge_k<<<NE / (4 * EPW), 256, 0, stream>>>(u, src, dst, rtab, masks);

    // gate GEMM + fused GRU epilogue -> out (M=20000, N=512, K=256)
    {
        dim3 grid(4, (NN + 127) / 128);
        gemm_gates<<<grid, 256, 0, stream>>>(feat, h, B2h, B2l, bias2, masks, W_comb, out);
    }
}